// Round 17
// baseline (1090.841 us; speedup 1.0000x reference)
//
#include <hip/hip_runtime.h>

// PositionAwareAttention: S=8192, B=64, D=512, A=256, all fp32 I/O.
// R17: producer/consumer WAVES x 2 independent blocks/CU.
//   waves 0-3 (consumers): R12's proven K-loop (wave = 32 rows x 64 acols,
//     B-frags streamed from packed global W) + epilogue -> scorep[i&1].
//   waves 4-5 (producers): own the whole serial remainder: final-add of tile
//     i-2, softmax+wsum of tile i-1 (from LDS buf (i-1)&1), then stage tile
//     i+1 (HBM) -> their vmcnt waits never stall consumers.
// 384 thr, LDS 73 KB -> 2 blocks/CU (12 waves/CU, 3/SIMD, mixed roles per
// SIMD = overlap). Persistent: 512 blocks x 32 tiles. Hazards: scorep & part
// double-buffered by tile parity; stage rows == wsum rows per producer wave
// (per-wave LDS ops are in-order); barriers block-uniform.
// k3 combines 256 tile-partials per b. bt omitted (softmax shift-invariant).

#define S_DIM 8192
#define B_DIM 64
#define D_DIM 512
#define A_DIM 256
#define BM 32
#define NTILES 256            // S / BM
#define TPB 32                // tiles per block
#define NBLK 512              // 64 b x 8 sgrp -> 2 blocks/CU

typedef _Float16 half8 __attribute__((ext_vector_type(8)));
typedef float f32x4 __attribute__((ext_vector_type(4)));

// LDS: xs dbuf 2*32768 + scorep dbuf 2*512B + part dbuf 2*4096
#define SMEM_MAIN (65536 + 1024 + 8192)

__device__ __forceinline__ float tanh_fast(float x) {
  // tanh(x) = 1 - 2/(exp(2x)+1); exp->inf/0 saturates correctly to +/-1
  float e = __expf(2.0f * x);
  return 1.0f - 2.0f * __builtin_amdgcn_rcpf(e + 1.0f);
}

// Pack Wx (A=256 x K=512 f32) -> fp16 fragment tiles (R4 layout).
// elem (a=ta*16+fr, k=tk*32+fg*8+j) at Wp[(ta*16+tk)*512 + (fg*16+fr)*8 + j]
__global__ void __launch_bounds__(256)
convw_kernel(const float* __restrict__ Wx, _Float16* __restrict__ Wp) {
  const int idx = (blockIdx.x * 256 + threadIdx.x) * 8;
  const int a = idx >> 9;
  const int k = idx & 511;
  f32x4 va = *(const f32x4*)(Wx + idx);
  f32x4 vb = *(const f32x4*)(Wx + idx + 4);
  half8 hx;
#pragma unroll
  for (int i = 0; i < 4; ++i) { hx[i] = (_Float16)va[i]; hx[4 + i] = (_Float16)vb[i]; }
  const int ta = a >> 4, fr = a & 15;
  const int tk = k >> 5, fg = (k >> 3) & 3;
  *(half8*)(Wp + (ta * 16 + tk) * 512 + (fg * 16 + fr) * 8) = hx;
}

__global__ void __launch_bounds__(256)
whb_kernel(const float* __restrict__ h, const float* __restrict__ Wh,
           const float* __restrict__ bx, float* __restrict__ whb) {
  __shared__ float hs[D_DIM];
  const int b = blockIdx.x, tid = threadIdx.x;
  hs[tid] = h[b * D_DIM + tid];
  hs[tid + 256] = h[b * D_DIM + 256 + tid];
  __syncthreads();
  const int g = tid >> 4, i = tid & 15;
  for (int pass = 0; pass < 16; ++pass) {
    const int a = pass * 16 + g;
    const f32x4* wrow = (const f32x4*)(Wh + (size_t)a * D_DIM);
    float dot = 0.f;
#pragma unroll
    for (int k = 0; k < 8; ++k) {
      f32x4 wv = wrow[i + k * 16];
      f32x4 hv = *(const f32x4*)(hs + (i + k * 16) * 4);
      dot += wv[0] * hv[0] + wv[1] * hv[1] + wv[2] * hv[2] + wv[3] * hv[3];
    }
#pragma unroll
    for (int mask = 1; mask < 16; mask <<= 1) dot += __shfl_xor(dot, mask, 64);
    if (i == 0) whb[b * A_DIM + a] = dot + bx[a];
  }
}

__global__ void __launch_bounds__(384, 3)
paa_main(const float* __restrict__ x, const _Float16* __restrict__ Wp,
         const float* __restrict__ whb, const float* __restrict__ Wt,
         float* __restrict__ m_arr, float* __restrict__ l_arr,
         float* __restrict__ acc_arr) {
  extern __shared__ char smem[];
  _Float16* xs0 = (_Float16*)smem;                    // [32][512] f16, buf 0
  _Float16* xs1 = (_Float16*)(smem + 32768);          // buf 1
  float* scorep = (float*)(smem + 65536);             // [2][4*32]
  float* part   = (float*)(smem + 65536 + 1024);      // [2][2][512]

  const int tid = threadIdx.x;            // 0..383
  const int lane = tid & 63;
  const int wv = tid >> 6;                // 0..5
  const int b = blockIdx.x & 63;
  const int sgrp = blockIdx.x >> 6;       // 0..7
  const int t0 = sgrp * TPB;

  const int fr = lane & 15, fg = lane >> 4;
  const int akey = fr & 7;

  // consumer geometry (wv<4): R12's wave layout (32 rows x 64 acols)
  const _Float16* wp = Wp + wv * (4 * 16 * 512) + lane * 8;
  float wt_a[4], whb_a[4];
  if (wv < 4) {
#pragma unroll
    for (int nf = 0; nf < 4; ++nf) {
      wt_a[nf]  = Wt[wv * 64 + nf * 16 + fr];
      whb_a[nf] = whb[b * A_DIM + wv * 64 + nf * 16 + fr];
    }
  }

  // producer geometry (wv>=4): ptid 0..127; prow = ptid>>2 (4 thr/row),
  // quad = ptid&3 -> chunks quad*16..+15. Stage rows == wsum rows per wave.
  const int ptid = tid - 256;
  const int prow = (ptid >= 0) ? (ptid >> 2) : 0;
  const int quad = (ptid >= 0) ? (ptid & 3) : 0;
  const int pw = wv - 4;                  // 0 or 1

  auto stage_tile = [&](int tile, _Float16* buf) {
    const float* rp = x + ((size_t)(tile * BM + prow) * B_DIM + b) * D_DIM;
    f32x4 sa[4], sb[4];
#pragma unroll
    for (int c = 0; c < 4; ++c) {
      sa[c] = *(const f32x4*)(rp + (quad * 16 + c) * 8);
      sb[c] = *(const f32x4*)(rp + (quad * 16 + c) * 8 + 4);
    }
#pragma unroll
    for (int c = 0; c < 4; ++c) {
      half8 hx;
#pragma unroll
      for (int j = 0; j < 4; ++j) { hx[j] = (_Float16)sa[c][j]; hx[4 + j] = (_Float16)sb[c][j]; }
      const int ch = quad * 16 + c;
      *(half8*)(buf + prow * D_DIM + ((ch ^ (prow & 7)) * 8)) = hx;
    }
#pragma unroll
    for (int c = 0; c < 4; ++c) {
      sa[c] = *(const f32x4*)(rp + (quad * 16 + 4 + c) * 8);
      sb[c] = *(const f32x4*)(rp + (quad * 16 + 4 + c) * 8 + 4);
    }
#pragma unroll
    for (int c = 0; c < 4; ++c) {
      half8 hx;
#pragma unroll
      for (int j = 0; j < 4; ++j) { hx[j] = (_Float16)sa[c][j]; hx[4 + j] = (_Float16)sb[c][j]; }
      const int ch = quad * 16 + 4 + c;
      *(half8*)(buf + prow * D_DIM + ((ch ^ (prow & 7)) * 8)) = hx;
    }
#pragma unroll
    for (int c = 0; c < 8; ++c) {
      sa[c & 3] = *(const f32x4*)(rp + (quad * 16 + 8 + c) * 8);
      sb[c & 3] = *(const f32x4*)(rp + (quad * 16 + 8 + c) * 8 + 4);
      if ((c & 3) == 3) {
#pragma unroll
        for (int cc = 0; cc < 4; ++cc) {
          half8 hx;
#pragma unroll
          for (int j = 0; j < 4; ++j) { hx[j] = (_Float16)sa[cc][j]; hx[4 + j] = (_Float16)sb[cc][j]; }
          const int ch = quad * 16 + 8 + (c - 3) + cc;
          *(half8*)(buf + prow * D_DIM + ((ch ^ (prow & 7)) * 8)) = hx;
        }
      }
    }
  };

  // ---- prologue: producers stage tile t0 into buf0
  if (wv >= 4) stage_tile(t0, xs0);
  __syncthreads();

  for (int i = 0; i < TPB; ++i) {
    const int par = i & 1;
    _Float16* xcur = par ? xs1 : xs0;

    if (wv < 4) {
      // ============ consumer: K-loop + epilogue (R12's proven path) ============
      f32x4 acc[2][4];
#pragma unroll
      for (int mi = 0; mi < 2; ++mi)
#pragma unroll
        for (int nf = 0; nf < 4; ++nf) acc[mi][nf] = (f32x4){0.f, 0.f, 0.f, 0.f};
#pragma unroll
      for (int tk = 0; tk < 16; ++tk) {
        const int slot = ((tk * 4 + fg) ^ akey) * 8;
        half8 af0 = *(const half8*)(xcur + (fr) * D_DIM + slot);
        half8 af1 = *(const half8*)(xcur + (16 + fr) * D_DIM + slot);
        half8 bf0 = *(const half8*)(wp + (0 * 16 + tk) * 512);
        half8 bf1 = *(const half8*)(wp + (1 * 16 + tk) * 512);
        half8 bf2 = *(const half8*)(wp + (2 * 16 + tk) * 512);
        half8 bf3 = *(const half8*)(wp + (3 * 16 + tk) * 512);
        acc[0][0] = __builtin_amdgcn_mfma_f32_16x16x32_f16(af0, bf0, acc[0][0], 0, 0, 0);
        acc[0][1] = __builtin_amdgcn_mfma_f32_16x16x32_f16(af0, bf1, acc[0][1], 0, 0, 0);
        acc[0][2] = __builtin_amdgcn_mfma_f32_16x16x32_f16(af0, bf2, acc[0][2], 0, 0, 0);
        acc[0][3] = __builtin_amdgcn_mfma_f32_16x16x32_f16(af0, bf3, acc[0][3], 0, 0, 0);
        acc[1][0] = __builtin_amdgcn_mfma_f32_16x16x32_f16(af1, bf0, acc[1][0], 0, 0, 0);
        acc[1][1] = __builtin_amdgcn_mfma_f32_16x16x32_f16(af1, bf1, acc[1][1], 0, 0, 0);
        acc[1][2] = __builtin_amdgcn_mfma_f32_16x16x32_f16(af1, bf2, acc[1][2], 0, 0, 0);
        acc[1][3] = __builtin_amdgcn_mfma_f32_16x16x32_f16(af1, bf3, acc[1][3], 0, 0, 0);
      }
      float pt[2][4];
#pragma unroll
      for (int mi = 0; mi < 2; ++mi)
#pragma unroll
        for (int r = 0; r < 4; ++r) pt[mi][r] = 0.f;
#pragma unroll
      for (int nf = 0; nf < 4; ++nf)
#pragma unroll
        for (int mi = 0; mi < 2; ++mi)
#pragma unroll
          for (int r = 0; r < 4; ++r)
            pt[mi][r] += wt_a[nf] * tanh_fast(acc[mi][nf][r] + whb_a[nf]);
#pragma unroll
      for (int mask = 1; mask < 16; mask <<= 1)
#pragma unroll
        for (int mi = 0; mi < 2; ++mi)
#pragma unroll
          for (int r = 0; r < 4; ++r) pt[mi][r] += __shfl_xor(pt[mi][r], mask, 64);
      if (fr == 0) {
#pragma unroll
        for (int mi = 0; mi < 2; ++mi)
#pragma unroll
          for (int r = 0; r < 4; ++r)
            scorep[par * 128 + wv * BM + mi * 16 + fg * 4 + r] = pt[mi][r];
      }
    } else {
      // ============ producer: final-add(i-2) | softmax+wsum(i-1) | stage(i+1) ============
      const int ppar = par ^ 1;           // parity of tile i-1 (and i+1)
      if (i >= 2) {
        // final-add of tile i-2 (parity == par): part[par][0][c]+part[par][1][c]
        const int c0 = ptid * 4;          // 128 thr x 4 cols = 512
        f32x4 p0 = *(const f32x4*)(part + par * 1024 + c0);
        f32x4 p1 = *(const f32x4*)(part + par * 1024 + 512 + c0);
        f32x4 s = {p0[0] + p1[0], p0[1] + p1[1], p0[2] + p1[2], p0[3] + p1[3]};
        *(f32x4*)(acc_arr + ((size_t)(b * NTILES + t0 + i - 2)) * D_DIM + c0) = s;
      }
      if (i >= 1) {
        // softmax + wsum partial of tile i-1 from buf ppar
        _Float16* xprev = ppar ? xs1 : xs0;
        const int rl = lane & 31;
        float sv = scorep[ppar * 128 + rl] + scorep[ppar * 128 + 32 + rl]
                 + scorep[ppar * 128 + 64 + rl] + scorep[ppar * 128 + 96 + rl];
        float m = sv;
#pragma unroll
        for (int mask = 1; mask < 32; mask <<= 1) m = fmaxf(m, __shfl_xor(m, mask, 64));
        float p = __expf(sv - m);
        float lsum = p;
#pragma unroll
        for (int mask = 1; mask < 32; mask <<= 1) lsum += __shfl_xor(lsum, mask, 64);
        if (pw == 0 && lane == 0) {
          m_arr[b * NTILES + t0 + i - 1] = m;
          l_arr[b * NTILES + t0 + i - 1] = lsum;
        }
        // wsum over THIS wave's rows (pw*16..+15), lane owns chunk = lane
        float wacc[8];
#pragma unroll
        for (int j = 0; j < 8; ++j) wacc[j] = 0.f;
#pragma unroll
        for (int k = 0; k < 16; ++k) {
          const int row = pw * 16 + k;
          const float pr = __shfl(p, row, 64);
          half8 xv = *(const half8*)(xprev + row * D_DIM + ((lane ^ (row & 7)) * 8));
#pragma unroll
          for (int j = 0; j < 8; ++j) wacc[j] += pr * (float)xv[j];
        }
        float* pb = part + ppar * 1024 + pw * 512 + lane * 8;
        *(f32x4*)(pb) = (f32x4){wacc[0], wacc[1], wacc[2], wacc[3]};
        *(f32x4*)(pb + 4) = (f32x4){wacc[4], wacc[5], wacc[6], wacc[7]};
      }
      if (i + 1 < TPB) {
        // stage tile i+1 into buf ppar (same rows this wave just wsum-read;
        // per-wave LDS ops are in-order -> no race)
        stage_tile(t0 + i + 1, ppar ? xs1 : xs0);
      }
    }

    __syncthreads();
  }

  // ---- epilogue: finish tile TPB-1 (and TPB-2's final-add)
  if (wv >= 4) {
    const int lpar = (TPB - 1) & 1;       // parity of last tile
    {
      // final-add of tile TPB-2 (parity == lpar^1)
      const int c0 = ptid * 4;
      f32x4 p0 = *(const f32x4*)(part + (lpar ^ 1) * 1024 + c0);
      f32x4 p1 = *(const f32x4*)(part + (lpar ^ 1) * 1024 + 512 + c0);
      f32x4 s = {p0[0] + p1[0], p0[1] + p1[1], p0[2] + p1[2], p0[3] + p1[3]};
      *(f32x4*)(acc_arr + ((size_t)(b * NTILES + t0 + TPB - 2)) * D_DIM + c0) = s;
    }
    {
      _Float16* xprev = lpar ? xs1 : xs0;
      const int rl = lane & 31;
      float sv = scorep[lpar * 128 + rl] + scorep[lpar * 128 + 32 + rl]
               + scorep[lpar * 128 + 64 + rl] + scorep[lpar * 128 + 96 + rl];
      float m = sv;
#pragma unroll
      for (int mask = 1; mask < 32; mask <<= 1) m = fmaxf(m, __shfl_xor(m, mask, 64));
      float p = __expf(sv - m);
      float lsum = p;
#pragma unroll
      for (int mask = 1; mask < 32; mask <<= 1) lsum += __shfl_xor(lsum, mask, 64);
      if (pw == 0 && lane == 0) {
        m_arr[b * NTILES + t0 + TPB - 1] = m;
        l_arr[b * NTILES + t0 + TPB - 1] = lsum;
      }
      float wacc[8];
#pragma unroll
      for (int j = 0; j < 8; ++j) wacc[j] = 0.f;
#pragma unroll
      for (int k = 0; k < 16; ++k) {
        const int row = pw * 16 + k;
        const float pr = __shfl(p, row, 64);
        half8 xv = *(const half8*)(xprev + row * D_DIM + ((lane ^ (row & 7)) * 8));
#pragma unroll
        for (int j = 0; j < 8; ++j) wacc[j] += pr * (float)xv[j];
      }
      float* pb = part + lpar * 1024 + pw * 512 + lane * 8;
      *(f32x4*)(pb) = (f32x4){wacc[0], wacc[1], wacc[2], wacc[3]};
      *(f32x4*)(pb + 4) = (f32x4){wacc[4], wacc[5], wacc[6], wacc[7]};
    }
  }
  __syncthreads();
  if (wv >= 4) {
    const int lpar = (TPB - 1) & 1;
    const int c0 = ptid * 4;
    f32x4 p0 = *(const f32x4*)(part + lpar * 1024 + c0);
    f32x4 p1 = *(const f32x4*)(part + lpar * 1024 + 512 + c0);
    f32x4 s = {p0[0] + p1[0], p0[1] + p1[1], p0[2] + p1[2], p0[3] + p1[3]};
    *(f32x4*)(acc_arr + ((size_t)(b * NTILES + t0 + TPB - 1)) * D_DIM + c0) = s;
  }
}

__global__ void __launch_bounds__(512)
combine_kernel(const float* __restrict__ m_arr, const float* __restrict__ l_arr,
               const float* __restrict__ acc_arr, float* __restrict__ out) {
  __shared__ float ml[NTILES], ls[NTILES], wl[NTILES];
  const int b = blockIdx.x, tid = threadIdx.x;
  if (tid < NTILES) {
    ml[tid] = m_arr[b * NTILES + tid];
    ls[tid] = l_arr[b * NTILES + tid];
  }
  __syncthreads();
  float M = -1e30f;
  for (int i = 0; i < NTILES; ++i) M = fmaxf(M, ml[i]);
  if (tid < NTILES) wl[tid] = __expf(ml[tid] - M);
  __syncthreads();
  float L = 0.f;
  for (int i = 0; i < NTILES; ++i) L += wl[i] * ls[i];
  float sum = 0.f;
  const size_t base = (size_t)b * NTILES * D_DIM + tid;
  for (int i = 0; i < NTILES; ++i) sum += wl[i] * acc_arr[base + (size_t)i * D_DIM];
  out[b * D_DIM + tid] = sum / L;
}

extern "C" void kernel_launch(void* const* d_in, const int* in_sizes, int n_in,
                              void* d_out, int out_size, void* d_ws, size_t ws_size,
                              hipStream_t stream) {
  const float* x = (const float*)d_in[0];
  const float* h = (const float*)d_in[1];
  const float* Wx = (const float*)d_in[2];
  const float* bx = (const float*)d_in[3];
  const float* Wh = (const float*)d_in[4];
  const float* Wt = (const float*)d_in[5];
  // d_in[6] = bt: unused (softmax shift-invariant)

  char* ws = (char*)d_ws;
  _Float16* Wp = (_Float16*)ws;                               // 262144 B (packed)
  float* whb = (float*)(ws + 262144);                         // 65536 B
  float* m_arr = (float*)(ws + 262144 + 65536);               // 65536 B
  float* l_arr = (float*)(ws + 262144 + 65536 + 65536);       // 65536 B
  float* acc_arr = (float*)(ws + 262144 + 3 * 65536);         // 33.6 MB

  hipFuncSetAttribute(reinterpret_cast<const void*>(paa_main),
                      hipFuncAttributeMaxDynamicSharedMemorySize, SMEM_MAIN);

  hipLaunchKernelGGL(convw_kernel, dim3(64), dim3(256), 0, stream, Wx, Wp);
  hipLaunchKernelGGL(whb_kernel, dim3(B_DIM), dim3(256), 0, stream, h, Wh, bx, whb);
  hipLaunchKernelGGL(paa_main, dim3(NBLK), dim3(384), SMEM_MAIN, stream,
                     x, Wp, whb, Wt, m_arr, l_arr, acc_arr);
  hipLaunchKernelGGL(combine_kernel, dim3(B_DIM), dim3(512), 0, stream,
                     m_arr, l_arr, acc_arr, (float*)d_out);
}

// Round 18
// 714.069 us; speedup vs baseline: 1.5276x; 1.5276x over previous
//
#include <hip/hip_runtime.h>

// PositionAwareAttention: S=8192, B=64, D=512, A=256, all fp32 I/O.
// R18: balanced producer/consumer waves (4:4, 512 thr, 2 blocks/CU).
// Per tile step, two barrier-phases:
//   A: consumers K-loop tk0-7 (L2 W-stream)  || producers softmax+wsum(i-1)
//   B: consumers K-loop tk8-15 + epilogue    || producers stage(i+1) (HBM)
// Stage writes the buffer wsum just vacated (parity (i-1)&1 == (i+1)&1),
// barrier-protected. HBM (producers) and L2 (consumers) live on different
// waves' vmcnt queues -> true overlap. R17's failure was 4:2 imbalance.
// All inner code reused from R12 (proven 368 us): K-loop, epilogue, wsum,
// staging map. k3 combines 256 partials per b. bt omitted (shift-invariant).

#define S_DIM 8192
#define B_DIM 64
#define D_DIM 512
#define A_DIM 256
#define BM 32
#define NTILES 256            // S / BM
#define TPB 32                // tiles per block
#define NBLK 512              // 64 b x 8 sgrp -> 2 blocks/CU

typedef _Float16 half8 __attribute__((ext_vector_type(8)));
typedef float f32x4 __attribute__((ext_vector_type(4)));

// LDS: xs dbuf 2*32768 + scorep dbuf 2*128 f32
#define SMEM_MAIN (65536 + 1024)

__device__ __forceinline__ float tanh_fast(float x) {
  // tanh(x) = 1 - 2/(exp(2x)+1); exp->inf/0 saturates correctly to +/-1
  float e = __expf(2.0f * x);
  return 1.0f - 2.0f * __builtin_amdgcn_rcpf(e + 1.0f);
}

// Pack Wx (A=256 x K=512 f32) -> fp16 fragment tiles (R4 layout).
// elem (a=ta*16+fr, k=tk*32+fg*8+j) at Wp[(ta*16+tk)*512 + (fg*16+fr)*8 + j]
__global__ void __launch_bounds__(256)
convw_kernel(const float* __restrict__ Wx, _Float16* __restrict__ Wp) {
  const int idx = (blockIdx.x * 256 + threadIdx.x) * 8;
  const int a = idx >> 9;
  const int k = idx & 511;
  f32x4 va = *(const f32x4*)(Wx + idx);
  f32x4 vb = *(const f32x4*)(Wx + idx + 4);
  half8 hx;
#pragma unroll
  for (int i = 0; i < 4; ++i) { hx[i] = (_Float16)va[i]; hx[4 + i] = (_Float16)vb[i]; }
  const int ta = a >> 4, fr = a & 15;
  const int tk = k >> 5, fg = (k >> 3) & 3;
  *(half8*)(Wp + (ta * 16 + tk) * 512 + (fg * 16 + fr) * 8) = hx;
}

__global__ void __launch_bounds__(256)
whb_kernel(const float* __restrict__ h, const float* __restrict__ Wh,
           const float* __restrict__ bx, float* __restrict__ whb) {
  __shared__ float hs[D_DIM];
  const int b = blockIdx.x, tid = threadIdx.x;
  hs[tid] = h[b * D_DIM + tid];
  hs[tid + 256] = h[b * D_DIM + 256 + tid];
  __syncthreads();
  const int g = tid >> 4, i = tid & 15;
  for (int pass = 0; pass < 16; ++pass) {
    const int a = pass * 16 + g;
    const f32x4* wrow = (const f32x4*)(Wh + (size_t)a * D_DIM);
    float dot = 0.f;
#pragma unroll
    for (int k = 0; k < 8; ++k) {
      f32x4 wv = wrow[i + k * 16];
      f32x4 hv = *(const f32x4*)(hs + (i + k * 16) * 4);
      dot += wv[0] * hv[0] + wv[1] * hv[1] + wv[2] * hv[2] + wv[3] * hv[3];
    }
#pragma unroll
    for (int mask = 1; mask < 16; mask <<= 1) dot += __shfl_xor(dot, mask, 64);
    if (i == 0) whb[b * A_DIM + a] = dot + bx[a];
  }
}

__global__ void __launch_bounds__(512, 4)
paa_main(const float* __restrict__ x, const _Float16* __restrict__ Wp,
         const float* __restrict__ whb, const float* __restrict__ Wt,
         float* __restrict__ m_arr, float* __restrict__ l_arr,
         float* __restrict__ acc_arr) {
  extern __shared__ char smem[];
  _Float16* xs0 = (_Float16*)smem;                    // [32][512] f16, buf 0
  _Float16* xs1 = (_Float16*)(smem + 32768);          // buf 1
  float* scorep = (float*)(smem + 65536);             // [2][4*32]

  const int tid = threadIdx.x;            // 0..511
  const int lane = tid & 63;
  const int wv = tid >> 6;                // 0..7
  const int b = blockIdx.x & 63;
  const int sgrp = blockIdx.x >> 6;       // 0..7
  const int t0 = sgrp * TPB;

  const int fr = lane & 15, fg = lane >> 4;
  const int akey = fr & 7;

  // ---- consumer geometry (wv<4): R12's wave layout (32 rows x 64 acols)
  const _Float16* wp = Wp + (wv & 3) * (4 * 16 * 512) + lane * 8;
  float wt_a[4], whb_a[4];
  if (wv < 4) {
#pragma unroll
    for (int nf = 0; nf < 4; ++nf) {
      wt_a[nf]  = Wt[wv * 64 + nf * 16 + fr];
      whb_a[nf] = whb[b * A_DIM + wv * 64 + nf * 16 + fr];
    }
  }

  // ---- producer geometry (wv>=4): R12's staging map on ptid 0..255
  const int ptid = (tid >= 256) ? (tid - 256) : 0;
  const int srow = ptid >> 3, sseg = ptid & 7;
  const int skey = srow & 7;
  const int pw = (wv >= 4) ? (wv - 4) : 0;   // 0..3

  auto stage_tile = [&](int tile, _Float16* buf) {
    const float* rp = x + ((size_t)(tile * BM + srow) * B_DIM + b) * D_DIM;
    f32x4 sa[4], sb[4];
#pragma unroll
    for (int p = 0; p < 4; ++p) {
      sa[p] = *(const f32x4*)(rp + p * 64 + sseg * 8);
      sb[p] = *(const f32x4*)(rp + p * 64 + sseg * 8 + 4);
    }
#pragma unroll
    for (int p = 0; p < 4; ++p) {
      half8 hx;
#pragma unroll
      for (int j = 0; j < 4; ++j) { hx[j] = (_Float16)sa[p][j]; hx[4 + j] = (_Float16)sb[p][j]; }
      const int ch = p * 8 + sseg;
      *(half8*)(buf + srow * D_DIM + ((ch ^ skey) * 8)) = hx;
    }
#pragma unroll
    for (int p = 0; p < 4; ++p) {
      sa[p] = *(const f32x4*)(rp + (4 + p) * 64 + sseg * 8);
      sb[p] = *(const f32x4*)(rp + (4 + p) * 64 + sseg * 8 + 4);
    }
#pragma unroll
    for (int p = 0; p < 4; ++p) {
      half8 hx;
#pragma unroll
      for (int j = 0; j < 4; ++j) { hx[j] = (_Float16)sa[p][j]; hx[4 + j] = (_Float16)sb[p][j]; }
      const int ch = (4 + p) * 8 + sseg;
      *(half8*)(buf + srow * D_DIM + ((ch ^ skey) * 8)) = hx;
    }
  };

  // softmax + wsum of tile (t_idx) from buffer `xb` / scorep bank `sp`.
  // Producer waves only; R12's wsum with ch = pw*16 + lane&15.
  auto finish_tile = [&](int t_idx, const _Float16* xb, const float* sp) {
    const int rl = lane & 31;
    float sv = sp[rl] + sp[32 + rl] + sp[64 + rl] + sp[96 + rl];
    float m = sv;
#pragma unroll
    for (int mask = 1; mask < 32; mask <<= 1) m = fmaxf(m, __shfl_xor(m, mask, 64));
    float p = __expf(sv - m);
    float lsum = p;
#pragma unroll
    for (int mask = 1; mask < 32; mask <<= 1) lsum += __shfl_xor(lsum, mask, 64);
    if (pw == 0 && lane == 0) {
      m_arr[b * NTILES + t_idx] = m;
      l_arr[b * NTILES + t_idx] = lsum;
    }
    const int q = lane >> 4;                 // 4 row-groups of 8
    const int ch = pw * 16 + (lane & 15);    // chunk 0..63
    float wacc[8];
#pragma unroll
    for (int j = 0; j < 8; ++j) wacc[j] = 0.f;
#pragma unroll
    for (int k = 0; k < 8; ++k) {
      const int row = q * 8 + k;
      const float pr = __shfl(p, row, 64);
      half8 xv = *(const half8*)(xb + row * D_DIM + ((ch ^ (row & 7)) * 8));
#pragma unroll
      for (int j = 0; j < 8; ++j) wacc[j] += pr * (float)xv[j];
    }
#pragma unroll
    for (int j = 0; j < 8; ++j) wacc[j] += __shfl_xor(wacc[j], 16, 64);
#pragma unroll
    for (int j = 0; j < 8; ++j) wacc[j] += __shfl_xor(wacc[j], 32, 64);
    if (lane < 16) {
      float* ob = acc_arr + ((size_t)(b * NTILES + t_idx)) * D_DIM + ch * 8;
      *(f32x4*)(ob) = (f32x4){wacc[0], wacc[1], wacc[2], wacc[3]};
      *(f32x4*)(ob + 4) = (f32x4){wacc[4], wacc[5], wacc[6], wacc[7]};
    }
  };

  // ---- prologue: producers stage tile t0 into xs0
  if (wv >= 4) stage_tile(t0, xs0);
  __syncthreads();

  for (int i = 0; i < TPB; ++i) {
    const int par = i & 1;
    _Float16* xcur = par ? xs1 : xs0;
    _Float16* xoth = par ? xs0 : xs1;     // holds tile i-1; becomes tile i+1

    f32x4 acc[2][4];
    if (wv < 4) {
#pragma unroll
      for (int mi = 0; mi < 2; ++mi)
#pragma unroll
        for (int nf = 0; nf < 4; ++nf) acc[mi][nf] = (f32x4){0.f, 0.f, 0.f, 0.f};
      // ---- phase A (consumers): K-loop tk 0..7
#pragma unroll
      for (int tk = 0; tk < 8; ++tk) {
        const int slot = ((tk * 4 + fg) ^ akey) * 8;
        half8 af0 = *(const half8*)(xcur + (fr) * D_DIM + slot);
        half8 af1 = *(const half8*)(xcur + (16 + fr) * D_DIM + slot);
        half8 bf0 = *(const half8*)(wp + (0 * 16 + tk) * 512);
        half8 bf1 = *(const half8*)(wp + (1 * 16 + tk) * 512);
        half8 bf2 = *(const half8*)(wp + (2 * 16 + tk) * 512);
        half8 bf3 = *(const half8*)(wp + (3 * 16 + tk) * 512);
        acc[0][0] = __builtin_amdgcn_mfma_f32_16x16x32_f16(af0, bf0, acc[0][0], 0, 0, 0);
        acc[0][1] = __builtin_amdgcn_mfma_f32_16x16x32_f16(af0, bf1, acc[0][1], 0, 0, 0);
        acc[0][2] = __builtin_amdgcn_mfma_f32_16x16x32_f16(af0, bf2, acc[0][2], 0, 0, 0);
        acc[0][3] = __builtin_amdgcn_mfma_f32_16x16x32_f16(af0, bf3, acc[0][3], 0, 0, 0);
        acc[1][0] = __builtin_amdgcn_mfma_f32_16x16x32_f16(af1, bf0, acc[1][0], 0, 0, 0);
        acc[1][1] = __builtin_amdgcn_mfma_f32_16x16x32_f16(af1, bf1, acc[1][1], 0, 0, 0);
        acc[1][2] = __builtin_amdgcn_mfma_f32_16x16x32_f16(af1, bf2, acc[1][2], 0, 0, 0);
        acc[1][3] = __builtin_amdgcn_mfma_f32_16x16x32_f16(af1, bf3, acc[1][3], 0, 0, 0);
      }
    } else if (i >= 1) {
      // ---- phase A (producers): softmax + wsum of tile i-1
      finish_tile(t0 + i - 1, xoth, scorep + (par ^ 1) * 128);
    }

    __syncthreads();   // end phase A: xoth free for restage; scorep[par^1] consumed

    if (wv < 4) {
      // ---- phase B (consumers): K-loop tk 8..15 + epilogue -> scorep[par]
#pragma unroll
      for (int tk = 8; tk < 16; ++tk) {
        const int slot = ((tk * 4 + fg) ^ akey) * 8;
        half8 af0 = *(const half8*)(xcur + (fr) * D_DIM + slot);
        half8 af1 = *(const half8*)(xcur + (16 + fr) * D_DIM + slot);
        half8 bf0 = *(const half8*)(wp + (0 * 16 + tk) * 512);
        half8 bf1 = *(const half8*)(wp + (1 * 16 + tk) * 512);
        half8 bf2 = *(const half8*)(wp + (2 * 16 + tk) * 512);
        half8 bf3 = *(const half8*)(wp + (3 * 16 + tk) * 512);
        acc[0][0] = __builtin_amdgcn_mfma_f32_16x16x32_f16(af0, bf0, acc[0][0], 0, 0, 0);
        acc[0][1] = __builtin_amdgcn_mfma_f32_16x16x32_f16(af0, bf1, acc[0][1], 0, 0, 0);
        acc[0][2] = __builtin_amdgcn_mfma_f32_16x16x32_f16(af0, bf2, acc[0][2], 0, 0, 0);
        acc[0][3] = __builtin_amdgcn_mfma_f32_16x16x32_f16(af0, bf3, acc[0][3], 0, 0, 0);
        acc[1][0] = __builtin_amdgcn_mfma_f32_16x16x32_f16(af1, bf0, acc[1][0], 0, 0, 0);
        acc[1][1] = __builtin_amdgcn_mfma_f32_16x16x32_f16(af1, bf1, acc[1][1], 0, 0, 0);
        acc[1][2] = __builtin_amdgcn_mfma_f32_16x16x32_f16(af1, bf2, acc[1][2], 0, 0, 0);
        acc[1][3] = __builtin_amdgcn_mfma_f32_16x16x32_f16(af1, bf3, acc[1][3], 0, 0, 0);
      }
      float pt[2][4];
#pragma unroll
      for (int mi = 0; mi < 2; ++mi)
#pragma unroll
        for (int r = 0; r < 4; ++r) pt[mi][r] = 0.f;
#pragma unroll
      for (int nf = 0; nf < 4; ++nf)
#pragma unroll
        for (int mi = 0; mi < 2; ++mi)
#pragma unroll
          for (int r = 0; r < 4; ++r)
            pt[mi][r] += wt_a[nf] * tanh_fast(acc[mi][nf][r] + whb_a[nf]);
#pragma unroll
      for (int mask = 1; mask < 16; mask <<= 1)
#pragma unroll
        for (int mi = 0; mi < 2; ++mi)
#pragma unroll
          for (int r = 0; r < 4; ++r) pt[mi][r] += __shfl_xor(pt[mi][r], mask, 64);
      if (fr == 0) {
#pragma unroll
        for (int mi = 0; mi < 2; ++mi)
#pragma unroll
          for (int r = 0; r < 4; ++r)
            scorep[par * 128 + wv * BM + mi * 16 + fg * 4 + r] = pt[mi][r];
      }
    } else if (i + 1 < TPB) {
      // ---- phase B (producers): stage tile i+1 into xoth (HBM)
      stage_tile(t0 + i + 1, xoth);
    }

    __syncthreads();   // end phase B: scorep[par] + next tile's xs ready
  }

  // ---- epilogue: finish the last tile
  if (wv >= 4) {
    const int lpar = (TPB - 1) & 1;
    finish_tile(t0 + TPB - 1, lpar ? xs1 : xs0, scorep + lpar * 128);
  }
}

__global__ void __launch_bounds__(512)
combine_kernel(const float* __restrict__ m_arr, const float* __restrict__ l_arr,
               const float* __restrict__ acc_arr, float* __restrict__ out) {
  __shared__ float ml[NTILES], ls[NTILES], wl[NTILES];
  const int b = blockIdx.x, tid = threadIdx.x;
  if (tid < NTILES) {
    ml[tid] = m_arr[b * NTILES + tid];
    ls[tid] = l_arr[b * NTILES + tid];
  }
  __syncthreads();
  float M = -1e30f;
  for (int i = 0; i < NTILES; ++i) M = fmaxf(M, ml[i]);
  if (tid < NTILES) wl[tid] = __expf(ml[tid] - M);
  __syncthreads();
  float L = 0.f;
  for (int i = 0; i < NTILES; ++i) L += wl[i] * ls[i];
  float sum = 0.f;
  const size_t base = (size_t)b * NTILES * D_DIM + tid;
  for (int i = 0; i < NTILES; ++i) sum += wl[i] * acc_arr[base + (size_t)i * D_DIM];
  out[b * D_DIM + tid] = sum / L;
}

extern "C" void kernel_launch(void* const* d_in, const int* in_sizes, int n_in,
                              void* d_out, int out_size, void* d_ws, size_t ws_size,
                              hipStream_t stream) {
  const float* x = (const float*)d_in[0];
  const float* h = (const float*)d_in[1];
  const float* Wx = (const float*)d_in[2];
  const float* bx = (const float*)d_in[3];
  const float* Wh = (const float*)d_in[4];
  const float* Wt = (const float*)d_in[5];
  // d_in[6] = bt: unused (softmax shift-invariant)

  char* ws = (char*)d_ws;
  _Float16* Wp = (_Float16*)ws;                               // 262144 B (packed)
  float* whb = (float*)(ws + 262144);                         // 65536 B
  float* m_arr = (float*)(ws + 262144 + 65536);               // 65536 B
  float* l_arr = (float*)(ws + 262144 + 65536 + 65536);       // 65536 B
  float* acc_arr = (float*)(ws + 262144 + 3 * 65536);         // 33.6 MB

  hipFuncSetAttribute(reinterpret_cast<const void*>(paa_main),
                      hipFuncAttributeMaxDynamicSharedMemorySize, SMEM_MAIN);

  hipLaunchKernelGGL(convw_kernel, dim3(64), dim3(256), 0, stream, Wx, Wp);
  hipLaunchKernelGGL(whb_kernel, dim3(B_DIM), dim3(256), 0, stream, h, Wh, bx, whb);
  hipLaunchKernelGGL(paa_main, dim3(NBLK), dim3(512), SMEM_MAIN, stream,
                     x, Wp, whb, Wt, m_arr, l_arr, acc_arr);
  hipLaunchKernelGGL(combine_kernel, dim3(B_DIM), dim3(512), 0, stream,
                     m_arr, l_arr, acc_arr, (float*)d_out);
}

// Round 19
// 416.365 us; speedup vs baseline: 2.6199x; 1.7150x over previous
//
#include <hip/hip_runtime.h>

// PositionAwareAttention: S=8192, B=64, D=512, A=256, all fp32 I/O.
// R19 = R12's proven structure (die-after-one-tile, one-shot stage, packed-W
// streamed from L2, swizzled fp16 LDS tile, fold epilogue, shuffle wsum)
// scaled to BM=64: W-L2 traffic per output row HALVES (each block reads the
// 256 KB packed W once for 64 rows instead of 32). 512 thr, 8 waves x
// (64 rows x 32 acols) -> every W byte read exactly once per block.
// LDS 67.6 KB -> 2 blocks/CU; launch_bounds(512,4) caps VGPR at 128
// (audited: acc 32 + frags 32 + stage 32 + addr/consts ~24 = ~120).
// k3 combines 128 tile-partials per b. bt omitted (softmax shift-invariant).

#define S_DIM 8192
#define B_DIM 64
#define D_DIM 512
#define A_DIM 256
#define BM 64
#define NTILES 128            // S / BM

typedef _Float16 half8 __attribute__((ext_vector_type(8)));
typedef float f32x4 __attribute__((ext_vector_type(4)));

__device__ __forceinline__ float tanh_fast(float x) {
  // tanh(x) = 1 - 2/(exp(2x)+1); exp->inf/0 saturates correctly to +/-1
  float e = __expf(2.0f * x);
  return 1.0f - 2.0f * __builtin_amdgcn_rcpf(e + 1.0f);
}

// Pack Wx (A=256 x K=512 f32) -> fp16 fragment tiles (R4 layout).
// elem (a=ta*16+fr, k=tk*32+fg*8+j) at Wp[(ta*16+tk)*512 + (fg*16+fr)*8 + j]
__global__ void __launch_bounds__(256)
convw_kernel(const float* __restrict__ Wx, _Float16* __restrict__ Wp) {
  const int idx = (blockIdx.x * 256 + threadIdx.x) * 8;
  const int a = idx >> 9;
  const int k = idx & 511;
  f32x4 va = *(const f32x4*)(Wx + idx);
  f32x4 vb = *(const f32x4*)(Wx + idx + 4);
  half8 hx;
#pragma unroll
  for (int i = 0; i < 4; ++i) { hx[i] = (_Float16)va[i]; hx[4 + i] = (_Float16)vb[i]; }
  const int ta = a >> 4, fr = a & 15;
  const int tk = k >> 5, fg = (k >> 3) & 3;
  *(half8*)(Wp + (ta * 16 + tk) * 512 + (fg * 16 + fr) * 8) = hx;
}

__global__ void __launch_bounds__(256)
whb_kernel(const float* __restrict__ h, const float* __restrict__ Wh,
           const float* __restrict__ bx, float* __restrict__ whb) {
  __shared__ float hs[D_DIM];
  const int b = blockIdx.x, tid = threadIdx.x;
  hs[tid] = h[b * D_DIM + tid];
  hs[tid + 256] = h[b * D_DIM + 256 + tid];
  __syncthreads();
  const int g = tid >> 4, i = tid & 15;
  for (int pass = 0; pass < 16; ++pass) {
    const int a = pass * 16 + g;
    const f32x4* wrow = (const f32x4*)(Wh + (size_t)a * D_DIM);
    float dot = 0.f;
#pragma unroll
    for (int k = 0; k < 8; ++k) {
      f32x4 wv = wrow[i + k * 16];
      f32x4 hv = *(const f32x4*)(hs + (i + k * 16) * 4);
      dot += wv[0] * hv[0] + wv[1] * hv[1] + wv[2] * hv[2] + wv[3] * hv[3];
    }
#pragma unroll
    for (int mask = 1; mask < 16; mask <<= 1) dot += __shfl_xor(dot, mask, 64);
    if (i == 0) whb[b * A_DIM + a] = dot + bx[a];
  }
}

__global__ void __launch_bounds__(512, 4)
paa_main(const float* __restrict__ x, const _Float16* __restrict__ Wp,
         const float* __restrict__ whb, const float* __restrict__ Wt,
         float* __restrict__ m_arr, float* __restrict__ l_arr,
         float* __restrict__ acc_arr) {
  __shared__ _Float16 xs[BM * D_DIM];     // [64][512] f16, 16B-chunk XOR swizzle (64 KB)
  __shared__ float scorep[8 * BM];        // [8 acol-groups][64 rows]

  const int tid = threadIdx.x;            // 0..511
  const int lane = tid & 63;
  const int wv = tid >> 6;                // 0..7 (wave = 64 rows x 32 acols)
  const int b = blockIdx.x;
  const int tile = blockIdx.y;

  const int fr = lane & 15, fg = lane >> 4;
  const int akey = fr & 7;
  // wave's packed-W base: acols [wv*32, wv*32+32) = ta {2wv, 2wv+1}
  const _Float16* wp = Wp + (wv * 2) * (16 * 512) + lane * 8;

  // epilogue constants, hoisted (per-lane acol scalars for nf=0..1)
  float wt_a[2], whb_a[2];
#pragma unroll
  for (int nf = 0; nf < 2; ++nf) {
    wt_a[nf]  = Wt[wv * 32 + nf * 16 + fr];
    whb_a[nf] = whb[b * A_DIM + wv * 32 + nf * 16 + fr];
  }

  // ---- stage: 64 rows x 512 f32 -> swizzled fp16 LDS (R12's map at 512 thr).
  // Thread = (srow 0..63, sseg 0..7); pair p covers f32 cols p*64+sseg*8..+7
  // -> fp16 chunk ch = p*8+sseg; p = 0..7 covers all 64 chunks.
  const int srow = tid >> 3, sseg = tid & 7;
  const int skey = srow & 7;
  {
    const float* rp = x + ((size_t)(tile * BM + srow) * B_DIM + b) * D_DIM;
    f32x4 sa[4], sb[4];
#pragma unroll
    for (int p = 0; p < 4; ++p) {
      sa[p] = *(const f32x4*)(rp + p * 64 + sseg * 8);
      sb[p] = *(const f32x4*)(rp + p * 64 + sseg * 8 + 4);
    }
#pragma unroll
    for (int p = 0; p < 4; ++p) {
      half8 hx;
#pragma unroll
      for (int j = 0; j < 4; ++j) { hx[j] = (_Float16)sa[p][j]; hx[4 + j] = (_Float16)sb[p][j]; }
      const int ch = p * 8 + sseg;
      *(half8*)(xs + srow * D_DIM + ((ch ^ skey) * 8)) = hx;
    }
#pragma unroll
    for (int p = 0; p < 4; ++p) {
      sa[p] = *(const f32x4*)(rp + (4 + p) * 64 + sseg * 8);
      sb[p] = *(const f32x4*)(rp + (4 + p) * 64 + sseg * 8 + 4);
    }
#pragma unroll
    for (int p = 0; p < 4; ++p) {
      half8 hx;
#pragma unroll
      for (int j = 0; j < 4; ++j) { hx[j] = (_Float16)sa[p][j]; hx[4 + j] = (_Float16)sb[p][j]; }
      const int ch = (4 + p) * 8 + sseg;
      *(half8*)(xs + srow * D_DIM + ((ch ^ skey) * 8)) = hx;
    }
  }
  __syncthreads();

  // ---- K-loop: A-frags (4 row-groups) from LDS, B-frags (2) from packed L2
  f32x4 acc[4][2];
#pragma unroll
  for (int mf = 0; mf < 4; ++mf)
#pragma unroll
    for (int nf = 0; nf < 2; ++nf) acc[mf][nf] = (f32x4){0.f, 0.f, 0.f, 0.f};
#pragma unroll
  for (int tk = 0; tk < 16; ++tk) {
    const int slot = ((tk * 4 + fg) ^ akey) * 8;
    half8 af0 = *(const half8*)(xs + (fr) * D_DIM + slot);
    half8 af1 = *(const half8*)(xs + (16 + fr) * D_DIM + slot);
    half8 af2 = *(const half8*)(xs + (32 + fr) * D_DIM + slot);
    half8 af3 = *(const half8*)(xs + (48 + fr) * D_DIM + slot);
    half8 bf0 = *(const half8*)(wp + (0 * 16 + tk) * 512);
    half8 bf1 = *(const half8*)(wp + (1 * 16 + tk) * 512);
    acc[0][0] = __builtin_amdgcn_mfma_f32_16x16x32_f16(af0, bf0, acc[0][0], 0, 0, 0);
    acc[0][1] = __builtin_amdgcn_mfma_f32_16x16x32_f16(af0, bf1, acc[0][1], 0, 0, 0);
    acc[1][0] = __builtin_amdgcn_mfma_f32_16x16x32_f16(af1, bf0, acc[1][0], 0, 0, 0);
    acc[1][1] = __builtin_amdgcn_mfma_f32_16x16x32_f16(af1, bf1, acc[1][1], 0, 0, 0);
    acc[2][0] = __builtin_amdgcn_mfma_f32_16x16x32_f16(af2, bf0, acc[2][0], 0, 0, 0);
    acc[2][1] = __builtin_amdgcn_mfma_f32_16x16x32_f16(af2, bf1, acc[2][1], 0, 0, 0);
    acc[3][0] = __builtin_amdgcn_mfma_f32_16x16x32_f16(af3, bf0, acc[3][0], 0, 0, 0);
    acc[3][1] = __builtin_amdgcn_mfma_f32_16x16x32_f16(af3, bf1, acc[3][1], 0, 0, 0);
  }

  // ---- epilogue: score partial for this wave's 32 acols (C frag: row=fg*4+r)
  {
    float part[4][4];
#pragma unroll
    for (int mf = 0; mf < 4; ++mf)
#pragma unroll
      for (int r = 0; r < 4; ++r) part[mf][r] = 0.f;
#pragma unroll
    for (int nf = 0; nf < 2; ++nf)
#pragma unroll
      for (int mf = 0; mf < 4; ++mf)
#pragma unroll
        for (int r = 0; r < 4; ++r)
          part[mf][r] += wt_a[nf] * tanh_fast(acc[mf][nf][r] + whb_a[nf]);
#pragma unroll
    for (int mask = 1; mask < 16; mask <<= 1)
#pragma unroll
      for (int mf = 0; mf < 4; ++mf)
#pragma unroll
        for (int r = 0; r < 4; ++r) part[mf][r] += __shfl_xor(part[mf][r], mask, 64);
    if (fr == 0) {
#pragma unroll
      for (int mf = 0; mf < 4; ++mf)
#pragma unroll
        for (int r = 0; r < 4; ++r)
          scorep[wv * BM + mf * 16 + fg * 4 + r] = part[mf][r];
    }
  }
  __syncthreads();

  // ---- tile-local softmax (64 rows; lane = row; all waves redundant)
  float sv = 0.f;
#pragma unroll
  for (int w = 0; w < 8; ++w) sv += scorep[w * BM + lane];
  float m = sv;
#pragma unroll
  for (int mask = 1; mask < 64; mask <<= 1) m = fmaxf(m, __shfl_xor(m, mask, 64));
  float p = __expf(sv - m);
  float lsum = p;
#pragma unroll
  for (int mask = 1; mask < 64; mask <<= 1) lsum += __shfl_xor(lsum, mask, 64);
  if (tid == 0) {
    m_arr[b * NTILES + tile] = m;
    l_arr[b * NTILES + tile] = lsum;
  }

  // ---- weighted sum from resident tile: wave owns 8 chunks (64 cols)
  {
    const int q = lane >> 3;                 // 8 row-groups of 8
    const int ch = wv * 8 + (lane & 7);      // chunk 0..63
    float wacc[8];
#pragma unroll
    for (int j = 0; j < 8; ++j) wacc[j] = 0.f;
#pragma unroll
    for (int k = 0; k < 8; ++k) {
      const int row = q * 8 + k;
      const float pr = __shfl(p, row, 64);
      half8 xv = *(const half8*)(xs + row * D_DIM + ((ch ^ (row & 7)) * 8));
#pragma unroll
      for (int j = 0; j < 8; ++j) wacc[j] += pr * (float)xv[j];
    }
#pragma unroll
    for (int j = 0; j < 8; ++j) wacc[j] += __shfl_xor(wacc[j], 8, 64);
#pragma unroll
    for (int j = 0; j < 8; ++j) wacc[j] += __shfl_xor(wacc[j], 16, 64);
#pragma unroll
    for (int j = 0; j < 8; ++j) wacc[j] += __shfl_xor(wacc[j], 32, 64);
    if (lane < 8) {
      float* ob = acc_arr + ((size_t)(b * NTILES + tile)) * D_DIM + ch * 8;
      *(f32x4*)(ob) = (f32x4){wacc[0], wacc[1], wacc[2], wacc[3]};
      *(f32x4*)(ob + 4) = (f32x4){wacc[4], wacc[5], wacc[6], wacc[7]};
    }
  }
}

__global__ void __launch_bounds__(512)
combine_kernel(const float* __restrict__ m_arr, const float* __restrict__ l_arr,
               const float* __restrict__ acc_arr, float* __restrict__ out) {
  __shared__ float ml[NTILES], ls[NTILES], wl[NTILES];
  const int b = blockIdx.x, tid = threadIdx.x;
  if (tid < NTILES) {
    ml[tid] = m_arr[b * NTILES + tid];
    ls[tid] = l_arr[b * NTILES + tid];
  }
  __syncthreads();
  float M = -1e30f;
  for (int i = 0; i < NTILES; ++i) M = fmaxf(M, ml[i]);
  if (tid < NTILES) wl[tid] = __expf(ml[tid] - M);
  __syncthreads();
  float L = 0.f;
  for (int i = 0; i < NTILES; ++i) L += wl[i] * ls[i];
  float sum = 0.f;
  const size_t base = (size_t)b * NTILES * D_DIM + tid;
  for (int i = 0; i < NTILES; ++i) sum += wl[i] * acc_arr[base + (size_t)i * D_DIM];
  out[b * D_DIM + tid] = sum / L;
}

extern "C" void kernel_launch(void* const* d_in, const int* in_sizes, int n_in,
                              void* d_out, int out_size, void* d_ws, size_t ws_size,
                              hipStream_t stream) {
  const float* x = (const float*)d_in[0];
  const float* h = (const float*)d_in[1];
  const float* Wx = (const float*)d_in[2];
  const float* bx = (const float*)d_in[3];
  const float* Wh = (const float*)d_in[4];
  const float* Wt = (const float*)d_in[5];
  // d_in[6] = bt: unused (softmax shift-invariant)

  char* ws = (char*)d_ws;
  _Float16* Wp = (_Float16*)ws;                               // 262144 B (packed)
  float* whb = (float*)(ws + 262144);                         // 65536 B
  float* m_arr = (float*)(ws + 262144 + 65536);               // 65536 B
  float* l_arr = (float*)(ws + 262144 + 65536 + 65536);       // 65536 B
  float* acc_arr = (float*)(ws + 262144 + 3 * 65536);         // 16.8 MB

  hipLaunchKernelGGL(convw_kernel, dim3(64), dim3(256), 0, stream, Wx, Wp);
  hipLaunchKernelGGL(whb_kernel, dim3(B_DIM), dim3(256), 0, stream, h, Wh, bx, whb);
  hipLaunchKernelGGL(paa_main, dim3(B_DIM, NTILES), dim3(512), 0, stream,
                     x, Wp, whb, Wt, m_arr, l_arr, acc_arr);
  hipLaunchKernelGGL(combine_kernel, dim3(B_DIM), dim3(512), 0, stream,
                     m_arr, l_arr, acc_arr, (float*)d_out);
}